// Round 11
// baseline (51.574 us; speedup 1.0000x reference)
//
#include <hip/hip_runtime.h>
#include <math.h>

typedef _Float16 half8 __attribute__((ext_vector_type(8)));
typedef _Float16 h2 __attribute__((ext_vector_type(2)));
typedef float    f32x4 __attribute__((ext_vector_type(4)));
typedef unsigned int u32;
typedef unsigned long long u64;
typedef unsigned short u16;

#define BIGV 1e30f
#define RSTR 36   // uint2 per ring row (288B)

__device__ __forceinline__ u32 dpp_shr1(u32 oldv, u32 src) {
  return (u32)__builtin_amdgcn_update_dpp((int)oldv, (int)src, 0x138, 0xF, 0xF, false);
}
__device__ __forceinline__ float cvtlo(u32 v) {
  union { u16 u; _Float16 h; } c; c.u = (u16)v; return (float)c.h;
}
__device__ __forceinline__ u16 f2h(float f) {
  union { _Float16 h; u16 u; } c; c.h = (_Float16)f; return c.u;
}
__device__ __forceinline__ u32 pkrtz(float a, float b) {
  auto v = __builtin_amdgcn_cvt_pkrtz(a, b);
  union { decltype(v) h; u32 u; } c; c.h = v; return c.u;
}
__device__ __forceinline__ u32 funnel16(u32 hi, u32 lo, u32 sh) {
  return (u32)(((((u64)hi) << 32) | (u64)lo) >> sh);   // v_alignbit
}
__device__ __forceinline__ h2 as_h2(u32 u) { union { u32 u; h2 h; } x; x.u = u; return x.h; }

// 256-thr blocks, 2 pairs each (waves 0-1 produce, 2-3 consume), ~70KB LDS ->
// 2 independent blocks per CU: barrier/latency bubbles of one block are filled
// by the other block's waves on the same SIMD. Pipeline logic = R9 (validated).
__global__ __launch_bounds__(256) void dtw_pc4(
    const float* __restrict__ x,      // (16,16,1024)
    const float* __restrict__ patts,  // (64,16,64)
    float* __restrict__ out,          // (16,64,64,64)
    float w) {
  __shared__ uint4 xsq[2050];            // f16-packed x columns + zero block @2048
  __shared__ uint2 ring2[2 * 64 * RSTR]; // per-pair ring: 64 rows x 288B
  __shared__ u16   x2h16[1024];          // ||x_t||^2 as f16

  const int tid = threadIdx.x, lane = tid & 63, wv = tid >> 6;
  const int b = blockIdx.x >> 5, pg = blockIdx.x & 31;
  const int role = wv >> 1, pr = wv & 1;
  const int p = pg * 2 + pr;
  const int le = lane & 15, kq = lane >> 4;

  // ---- stage x: coalesced global loads -> f16 LDS (hw index t*16+d) ----
  {
    const float* xb = x + b * (16 * 1024);
    u16* xh = (u16*)xsq;
    for (int idx = tid; idx < 16384; idx += 256) {
      int d = idx >> 10, t = idx & 1023;
      xh[t * 16 + d] = f2h(xb[idx]);
    }
    if (tid == 0) { xsq[2048] = make_uint4(0,0,0,0); xsq[2049] = make_uint4(0,0,0,0); }
    __syncthreads();   // staging pass 1 visible
    for (int t = tid; t < 1024; t += 256) {
      uint4 a0 = xsq[2 * t], a1 = xsq[2 * t + 1];
      float s2 = __builtin_amdgcn_fdot2(as_h2(a0.x), as_h2(a0.x), 0.f, false);
      s2 = __builtin_amdgcn_fdot2(as_h2(a0.y), as_h2(a0.y), s2, false);
      s2 = __builtin_amdgcn_fdot2(as_h2(a0.z), as_h2(a0.z), s2, false);
      s2 = __builtin_amdgcn_fdot2(as_h2(a0.w), as_h2(a0.w), s2, false);
      s2 = __builtin_amdgcn_fdot2(as_h2(a1.x), as_h2(a1.x), s2, false);
      s2 = __builtin_amdgcn_fdot2(as_h2(a1.y), as_h2(a1.y), s2, false);
      s2 = __builtin_amdgcn_fdot2(as_h2(a1.z), as_h2(a1.z), s2, false);
      s2 = __builtin_amdgcn_fdot2(as_h2(a1.w), as_h2(a1.w), s2, false);
      x2h16[t] = f2h(s2);
    }
  }
  __syncthreads();   // B0: staging complete

  if (role == 0) {
    // ================= PRODUCER =================
    half8 bf[4];
    {
      const float* pp = patts + p * (16 * 64);
#pragma unroll
      for (int nb = 0; nb < 4; ++nb) {
        float pv[8]; float part = 0.f;
#pragma unroll
        for (int j = 0; j < 8; ++j) {
          float f = (kq < 2) ? pp[(8 * kq + j) * 64 + nb * 16 + le] : 0.f;
          pv[j] = f; part = fmaf(f, f, part);
        }
        part += __shfl_xor(part, 16, 64);
        part += __shfl_xor(part, 32, 64);
        u32 wd0 = pkrtz(-2.f * pv[0], -2.f * pv[1]);
        u32 wd1 = pkrtz(-2.f * pv[2], -2.f * pv[3]);
        u32 wd2 = pkrtz(-2.f * pv[4], -2.f * pv[5]);
        u32 wd3 = pkrtz(-2.f * pv[6], -2.f * pv[7]);
        if (kq == 2) { wd0 = 0x3C00u | ((u32)f2h(part) << 16); wd1 = 0; wd2 = 0; wd3 = 0; }
        union { uint4 q; half8 h; } bu; bu.q = make_uint4(wd0, wd1, wd2, wd3);
        bf[nb] = bu.h;
      }
    }
    int colp = 8 * kq;
    const int wpbase = pr * (64 * RSTR) + RSTR * le;

#define PRODUCE(T0) { \
    int aidx_ = (kq < 2) ? (2 * ((T0) + le) + kq) : 2048; \
    uint4 aq_ = xsq[aidx_]; \
    u32 x2b_ = (u32)x2h16[(T0) + le]; \
    aq_.x = (kq == 2) ? (x2b_ | 0x3C000000u) : aq_.x; \
    union { uint4 q; half8 h; } au_; au_.q = aq_; \
    int wb_ = wpbase + (colp >> 3); \
    bool mir_ = colp < 32; \
    _Pragma("unroll") \
    for (int nb_ = 0; nb_ < 4; ++nb_) { \
      f32x4 c_ = {0.f, 0.f, 0.f, 0.f}; \
      c_ = __builtin_amdgcn_mfma_f32_16x16x32_f16(au_.h, bf[nb_], c_, 0, 0, 0); \
      float d0_ = __builtin_amdgcn_sqrtf(fmaxf(c_[0], 1e-12f)); \
      float d1_ = __builtin_amdgcn_sqrtf(fmaxf(c_[1], 1e-12f)); \
      float d2_ = __builtin_amdgcn_sqrtf(fmaxf(c_[2], 1e-12f)); \
      float d3_ = __builtin_amdgcn_sqrtf(fmaxf(c_[3], 1e-12f)); \
      uint2 st_; st_.x = pkrtz(d0_, d1_); st_.y = pkrtz(d2_, d3_); \
      ring2[wb_ + (16 * RSTR) * nb_] = st_; \
      if (mir_) ring2[wb_ + (16 * RSTR) * nb_ + 32] = st_; \
    } \
    colp = (colp + 32) & 255; }

    PRODUCE(0); PRODUCE(16); PRODUCE(32); PRODUCE(48);   // lead = 4 tiles
    __syncthreads();   // B1: tiles 0-3 ready
#pragma unroll 1
    for (int k = 0; k < 30; ++k) {       // phase k: produce tiles 2k+4, 2k+5
      PRODUCE(32 * k + 64);
      PRODUCE(32 * k + 80);
      __syncthreads();
    }
    __syncthreads(); __syncthreads(); __syncthreads(); __syncthreads();  // idle phases 30-33

  } else {
    // ================= CONSUMER =================
    const int rcbase = pr * (64 * RSTR) + RSTR * lane;
    int colc = (((0 - lane) >> 2) << 3) & 255;
    const int ph = (0 - lane) & 3;
    const u32 shv = (u32)((ph & 1) * 16);
    const bool sel2 = (ph & 2) != 0;
    float prev = BIGV, shA = BIGV, shB = BIGV, pend = 0.f;
    const int bigbits = __float_as_int(BIGV);
    float* oprow = out + ((b * 64 + p) * 64 + lane) * 64;

#define LOADQ(Q0,Q1,Q2,Q3,Q4) { int ci_ = rcbase + (colc >> 3); \
    Q0 = ring2[ci_];     Q1 = ring2[ci_ + 1]; Q2 = ring2[ci_ + 2]; \
    Q3 = ring2[ci_ + 3]; Q4 = ring2[ci_ + 4]; \
    colc = (colc + 32) & 255; }

#define SHIFT(curv) { shB = shA; \
    shA = __int_as_float((int)dpp_shr1((u32)bigbits, (u32)__float_as_int(curv))); \
    prev = (curv); }

#define STEP_PRO(S, D) { float dist_ = (D); \
    float m_ = fminf(fminf(prev, shA), shB); \
    float ms_ = (m_ >= 0.5e30f) ? 0.f : m_; \
    float val_ = fmaf(w, ms_, dist_); \
    int t_ = (S) - lane; float cur_ = (t_ >= 0) ? val_ : BIGV; \
    SHIFT(cur_); }

#define STEP_MAIN(S, D) { float dist_ = (D); \
    float m_ = fminf(fminf(prev, shA), shB); \
    float cur_ = fmaf(w, m_, dist_); \
    SHIFT(cur_); }

    // epilogue: lane-consecutive t -> accumulate even-t, store float2 on odd-t
#define STEP_EPI(S, D) { float dist_ = (D); \
    float m_ = fminf(fminf(prev, shA), shB); \
    float val_ = fmaf(w, m_, dist_); \
    int t_ = (S) - lane; float cur_ = (t_ <= 1023) ? val_ : BIGV; \
    if ((t_ & 1) == 0) { pend = val_; } \
    else if ((u32)(t_ - 961) < 63u) { \
      *(float2*)(oprow + (t_ - 961)) = make_float2(pend, val_); } \
    SHIFT(cur_); }

#define EXTRACT8(Q0, Q1, Q2, Q3, Q4) \
    u32 W0_ = sel2 ? Q0.y : Q0.x, W1_ = sel2 ? Q1.x : Q0.y, \
        W2_ = sel2 ? Q1.y : Q1.x, W3_ = sel2 ? Q2.x : Q1.y, \
        W4_ = sel2 ? Q2.y : Q2.x, W5_ = sel2 ? Q3.x : Q2.y, \
        W6_ = sel2 ? Q3.y : Q3.x, W7_ = sel2 ? Q4.x : Q3.y, \
        W8_ = sel2 ? Q4.y : Q4.x; \
    u32 A0 = funnel16(W1_, W0_, shv), A1 = funnel16(W2_, W1_, shv), \
        A2 = funnel16(W3_, W2_, shv), A3 = funnel16(W4_, W3_, shv), \
        A4 = funnel16(W5_, W4_, shv), A5 = funnel16(W6_, W5_, shv), \
        A6 = funnel16(W7_, W6_, shv), A7 = funnel16(W8_, W7_, shv);

#define S16(S0, STP) \
    STP((S0)+0,  cvtlo(A0)); STP((S0)+1,  cvtlo(A0 >> 16)); \
    STP((S0)+2,  cvtlo(A1)); STP((S0)+3,  cvtlo(A1 >> 16)); \
    STP((S0)+4,  cvtlo(A2)); STP((S0)+5,  cvtlo(A2 >> 16)); \
    STP((S0)+6,  cvtlo(A3)); STP((S0)+7,  cvtlo(A3 >> 16)); \
    STP((S0)+8,  cvtlo(A4)); STP((S0)+9,  cvtlo(A4 >> 16)); \
    STP((S0)+10, cvtlo(A5)); STP((S0)+11, cvtlo(A5 >> 16)); \
    STP((S0)+12, cvtlo(A6)); STP((S0)+13, cvtlo(A6 >> 16)); \
    STP((S0)+14, cvtlo(A7)); STP((S0)+15, cvtlo(A7 >> 16));

#define SET_PRO(S0)  S16(S0, STEP_PRO)
#define SET_MAIN(S0) S16(S0, STEP_MAIN)
#define SET_EPI(S0)  S16(S0, STEP_EPI)

    // PHASE: prefetch next pair's quads FIRST, consume regs from last phase, barrier.
#define PHASE(C0,C1,C2,C3,C4,C5,C6,C7,C8,C9, L0,L1,L2,L3,L4,L5,L6,L7,L8,L9, S0, SETM) { \
    LOADQ(L0,L1,L2,L3,L4); LOADQ(L5,L6,L7,L8,L9); \
    { EXTRACT8(C0,C1,C2,C3,C4); SETM(S0); } \
    { EXTRACT8(C5,C6,C7,C8,C9); SETM((S0)+16); } \
    __syncthreads(); }

    __syncthreads();   // B1: tiles 0-3 ready
    uint2 a0,a1,a2,a3,a4,a5,a6,a7,a8,a9;
    uint2 b0,b1,b2,b3,b4,b5,b6,b7,b8,b9;
    LOADQ(a0,a1,a2,a3,a4); LOADQ(a5,a6,a7,a8,a9);   // tiles 0,1

    // phases 0,1: s in [0,64), BIG-check + t>=0 mask
    PHASE(a0,a1,a2,a3,a4,a5,a6,a7,a8,a9, b0,b1,b2,b3,b4,b5,b6,b7,b8,b9, 0,  SET_PRO);
    PHASE(b0,b1,b2,b3,b4,b5,b6,b7,b8,b9, a0,a1,a2,a3,a4,a5,a6,a7,a8,a9, 32, SET_PRO);
    // phases 2-29: s in [64,960), lean
#pragma unroll 1
    for (int j = 1; j < 15; ++j) {
      PHASE(a0,a1,a2,a3,a4,a5,a6,a7,a8,a9, b0,b1,b2,b3,b4,b5,b6,b7,b8,b9, 64*j,      SET_MAIN);
      PHASE(b0,b1,b2,b3,b4,b5,b6,b7,b8,b9, a0,a1,a2,a3,a4,a5,a6,a7,a8,a9, 64*j + 32, SET_MAIN);
    }
    // phases 30-33: s in [960,1088), paired direct stores + t<=1023 mask
    PHASE(a0,a1,a2,a3,a4,a5,a6,a7,a8,a9, b0,b1,b2,b3,b4,b5,b6,b7,b8,b9, 960,  SET_EPI);
    PHASE(b0,b1,b2,b3,b4,b5,b6,b7,b8,b9, a0,a1,a2,a3,a4,a5,a6,a7,a8,a9, 992,  SET_EPI);
    PHASE(a0,a1,a2,a3,a4,a5,a6,a7,a8,a9, b0,b1,b2,b3,b4,b5,b6,b7,b8,b9, 1024, SET_EPI);
    PHASE(b0,b1,b2,b3,b4,b5,b6,b7,b8,b9, a0,a1,a2,a3,a4,a5,a6,a7,a8,a9, 1056, SET_EPI);
  }
}

extern "C" void kernel_launch(void* const* d_in, const int* in_sizes, int n_in,
                              void* d_out, int out_size, void* d_ws, size_t ws_size,
                              hipStream_t stream) {
  const float* x     = (const float*)d_in[0];
  const float* patts = (const float*)d_in[1];
  float* out         = (float*)d_out;
  const float w = (float)exp(log(0.1) / 64.0);
  dim3 grid(512), block(256);
  hipLaunchKernelGGL(dtw_pc4, grid, block, 0, stream, x, patts, out, w);
}

// Round 12
// 45.587 us; speedup vs baseline: 1.1313x; 1.1313x over previous
//
#include <hip/hip_runtime.h>
#include <math.h>

typedef _Float16 half8 __attribute__((ext_vector_type(8)));
typedef _Float16 h2 __attribute__((ext_vector_type(2)));
typedef float    f32x4 __attribute__((ext_vector_type(4)));
typedef unsigned int u32;
typedef unsigned short u16;

#define BIGV 1e30f
#define RQ   57              // uint2 per ring row (456B; 114 words, gcd(114,32)=2)
#define ROWB 456
#define PAIRB (64 * ROWB)    // 29184 B per pair ring

__device__ __forceinline__ u32 dpp_shr1(u32 oldv, u32 src) {
  return (u32)__builtin_amdgcn_update_dpp((int)oldv, (int)src, 0x138, 0xF, 0xF, false);
}
__device__ __forceinline__ float cvtlo(u32 v) {
  union { u16 u; _Float16 h; } c; c.u = (u16)v; return (float)c.h;
}
__device__ __forceinline__ u16 f2h(float f) {
  union { _Float16 h; u16 u; } c; c.h = (_Float16)f; return c.u;
}
__device__ __forceinline__ u32 pkrtz(float a, float b) {
  auto v = __builtin_amdgcn_cvt_pkrtz(a, b);
  union { decltype(v) h; u32 u; } c; c.h = v; return c.u;
}
__device__ __forceinline__ h2 as_h2(u32 u) { union { u32 u; h2 h; } x; x.u = u; return x.h; }

// Stagger-2 wavefront: lane l computes cell (l, t=s-2l). Cross-lane dpp results
// are consumed 2 steps later -> off the critical path (chain = min3+fma only).
// P/C wave split as R9/R10; ring window 14 tiles (224 t), 456B rows, no mirror.
__global__ __launch_bounds__(512) void dtw_sg(
    const float* __restrict__ x,      // (16,16,1024)
    const float* __restrict__ patts,  // (64,16,64)
    float* __restrict__ out,          // (16,64,64,64)
    float wd) {
  __shared__ uint4 xsq[2050];
  __shared__ u16   x2h16[1024];
  __shared__ uint2 ring2[4 * 64 * RQ];   // 116736 B

  const int tid = threadIdx.x, lane = tid & 63, wv = tid >> 6;
  const int b = blockIdx.x >> 4, pg = blockIdx.x & 15;
  const int role = wv >> 2, pr = wv & 3;
  const int p = pg * 4 + pr;
  const int le = lane & 15, kq = lane >> 4;

  // ---- stage x ----
  {
    const float* xb = x + b * (16 * 1024);
    u16* xh = (u16*)xsq;
    for (int idx = tid; idx < 16384; idx += 512) {
      int d = idx >> 10, t = idx & 1023;
      xh[t * 16 + d] = f2h(xb[idx]);
    }
    if (tid == 0) { xsq[2048] = make_uint4(0,0,0,0); xsq[2049] = make_uint4(0,0,0,0); }
    __syncthreads();
    for (int t = tid; t < 1024; t += 512) {
      uint4 a0 = xsq[2 * t], a1 = xsq[2 * t + 1];
      float s2 = __builtin_amdgcn_fdot2(as_h2(a0.x), as_h2(a0.x), 0.f, false);
      s2 = __builtin_amdgcn_fdot2(as_h2(a0.y), as_h2(a0.y), s2, false);
      s2 = __builtin_amdgcn_fdot2(as_h2(a0.z), as_h2(a0.z), s2, false);
      s2 = __builtin_amdgcn_fdot2(as_h2(a0.w), as_h2(a0.w), s2, false);
      s2 = __builtin_amdgcn_fdot2(as_h2(a1.x), as_h2(a1.x), s2, false);
      s2 = __builtin_amdgcn_fdot2(as_h2(a1.y), as_h2(a1.y), s2, false);
      s2 = __builtin_amdgcn_fdot2(as_h2(a1.z), as_h2(a1.z), s2, false);
      s2 = __builtin_amdgcn_fdot2(as_h2(a1.w), as_h2(a1.w), s2, false);
      x2h16[t] = f2h(s2);
    }
  }
  __syncthreads();   // B0

  if (role == 0) {
    // ================= PRODUCER =================
    half8 bf[4];
    {
      const float* pp = patts + p * (16 * 64);
#pragma unroll
      for (int nb = 0; nb < 4; ++nb) {
        float pv[8]; float part = 0.f;
#pragma unroll
        for (int j = 0; j < 8; ++j) {
          float f = (kq < 2) ? pp[(8 * kq + j) * 64 + nb * 16 + le] : 0.f;
          pv[j] = f; part = fmaf(f, f, part);
        }
        part += __shfl_xor(part, 16, 64);
        part += __shfl_xor(part, 32, 64);
        u32 wd0 = pkrtz(-2.f * pv[0], -2.f * pv[1]);
        u32 wd1 = pkrtz(-2.f * pv[2], -2.f * pv[3]);
        u32 wd2 = pkrtz(-2.f * pv[4], -2.f * pv[5]);
        u32 wd3 = pkrtz(-2.f * pv[6], -2.f * pv[7]);
        if (kq == 2) { wd0 = 0x3C00u | ((u32)f2h(part) << 16); wd1 = 0; wd2 = 0; wd3 = 0; }
        union { uint4 q; half8 h; } bu; bu.q = make_uint4(wd0, wd1, wd2, wd3);
        bf[nb] = bu.h;
      }
    }
    int colp = 8 * kq;                       // byte col of (T0 + 4kq) mod 224, x2
    const int wpbase = pr * (64 * RQ) + RQ * le;

#define PRODUCE(T0) { \
    int aidx_ = (kq < 2) ? (2 * ((T0) + le) + kq) : 2048; \
    uint4 aq_ = xsq[aidx_]; \
    u32 x2b_ = (u32)x2h16[(T0) + le]; \
    aq_.x = (kq == 2) ? (x2b_ | 0x3C000000u) : aq_.x; \
    union { uint4 q; half8 h; } au_; au_.q = aq_; \
    int wb_ = wpbase + (colp >> 3); \
    _Pragma("unroll") \
    for (int nb_ = 0; nb_ < 4; ++nb_) { \
      f32x4 c_ = {0.f, 0.f, 0.f, 0.f}; \
      c_ = __builtin_amdgcn_mfma_f32_16x16x32_f16(au_.h, bf[nb_], c_, 0, 0, 0); \
      float d0_ = __builtin_amdgcn_sqrtf(fmaxf(c_[0], 1e-12f)); \
      float d1_ = __builtin_amdgcn_sqrtf(fmaxf(c_[1], 1e-12f)); \
      float d2_ = __builtin_amdgcn_sqrtf(fmaxf(c_[2], 1e-12f)); \
      float d3_ = __builtin_amdgcn_sqrtf(fmaxf(c_[3], 1e-12f)); \
      uint2 st_; st_.x = pkrtz(d0_, d1_); st_.y = pkrtz(d2_, d3_); \
      ring2[wb_ + 16 * RQ * nb_] = st_; \
    } \
    colp += 32; if (colp >= 448) colp -= 448; }

    PRODUCE(0); PRODUCE(16); PRODUCE(32); PRODUCE(48);   // lead 4 tiles
    __syncthreads();   // B1
#pragma unroll 1
    for (int k = 0; k < 30; ++k) {       // phase k: tiles 2k+4, 2k+5
      PRODUCE(32 * k + 64);
      PRODUCE(32 * k + 80);
      __syncthreads();
    }
    for (int k = 0; k < 6; ++k) __syncthreads();   // idle phases 30-35

  } else {
    // ================= CONSUMER (stagger-2) =================
    const char* crow = (const char*)ring2 + pr * PAIRB + lane * ROWB;
    const int  l2 = 2 * lane;
    u32 byte0 = (u32)((448 - 4 * lane) % 448);
    u32 colc  = byte0 & ~7u;
    const bool sel2 = (lane & 1) != 0;
    const int bigbits = __float_as_int(BIGV);
    float prev = BIGV, q1 = BIGV, q2 = BIGV, q3 = BIGV, pend = 0.f;
    float* oprow = out + ((b * 64 + p) * 64 + lane) * 64;

#define WRAP448(X) ((X) >= 448u ? (X) - 448u : (X))
#define LQ(DST, OFF) { u32 o_ = WRAP448((u32)(OFF)); DST = *(const uint2*)(crow + o_); }

    // MODE: 0 = prologue (BIG-check + t>=0 mask), 1 = main,
    //       2 = epi stores (t<=1023 guaranteed), 3 = epi stores + t<=1023 mask
#define DPS(S, D, MODE) { \
    float dist_ = (D); \
    float m_ = fminf(fminf(prev, q2), q3); \
    if ((MODE) == 0) m_ = (m_ >= 0.5e30f) ? 0.f : m_; \
    float val_ = fmaf(wd, m_, dist_); \
    float cur_ = val_; \
    if ((MODE) == 0) cur_ = ((S) >= l2) ? val_ : BIGV; \
    if ((MODE) == 3) cur_ = (l2 >= (S) - 1023) ? val_ : BIGV; \
    if ((MODE) >= 2) { \
      if (((S) & 1) == 0) { pend = val_; } \
      else { int t_ = (S) - l2; if ((u32)(t_ - 961) < 63u) \
        *(float2*)(oprow + (t_ - 961)) = make_float2(pend, val_); } \
    } \
    q3 = q2; q2 = q1; \
    q1 = __int_as_float((int)dpp_shr1((u32)bigbits, (u32)__float_as_int(cur_))); \
    prev = cur_; }

#define G16(G0, G1, G2, G3, G4, S0, MODE) { \
    u32 w0 = sel2 ? G0.y : G0.x, w1 = sel2 ? G1.x : G0.y; \
    u32 w2 = sel2 ? G1.y : G1.x, w3 = sel2 ? G2.x : G1.y; \
    u32 w4 = sel2 ? G2.y : G2.x, w5 = sel2 ? G3.x : G2.y; \
    u32 w6 = sel2 ? G3.y : G3.x, w7 = sel2 ? G4.x : G3.y; \
    DPS((S0)+0,  cvtlo(w0), MODE); DPS((S0)+1,  cvtlo(w0 >> 16), MODE); \
    DPS((S0)+2,  cvtlo(w1), MODE); DPS((S0)+3,  cvtlo(w1 >> 16), MODE); \
    DPS((S0)+4,  cvtlo(w2), MODE); DPS((S0)+5,  cvtlo(w2 >> 16), MODE); \
    DPS((S0)+6,  cvtlo(w3), MODE); DPS((S0)+7,  cvtlo(w3 >> 16), MODE); \
    DPS((S0)+8,  cvtlo(w4), MODE); DPS((S0)+9,  cvtlo(w4 >> 16), MODE); \
    DPS((S0)+10, cvtlo(w5), MODE); DPS((S0)+11, cvtlo(w5 >> 16), MODE); \
    DPS((S0)+12, cvtlo(w6), MODE); DPS((S0)+13, cvtlo(w6 >> 16), MODE); \
    DPS((S0)+14, cvtlo(w7), MODE); DPS((S0)+15, cvtlo(w7 >> 16), MODE); }

    // Phase: load own 9th quad (tile 2k+2, ready post-barrier), compute group 1,
    // prefetch next phase's quads 1-7 (tiles <= 2k+3), compute group 2, barrier.
#define PHASE9(C0,C1,C2,C3,C4,C5,C6,C7, D8, N1,N2,N3,N4,N5,N6,N7, S0, MODE) { \
    LQ(D8, colc + 64); \
    G16(C0, C1, C2, C3, C4, S0, MODE); \
    LQ(N1, colc + 72);  LQ(N2, colc + 80);  LQ(N3, colc + 88); \
    LQ(N4, colc + 96);  LQ(N5, colc + 104); LQ(N6, colc + 112); LQ(N7, colc + 120); \
    G16(C4, C5, C6, C7, D8, (S0) + 16, MODE); \
    colc = WRAP448(colc + 64); \
    __builtin_amdgcn_s_barrier(); }

    __builtin_amdgcn_s_barrier();   // B1: tiles 0-3 ready
    uint2 a0,a1,a2,a3,a4,a5,a6,a7,a8, b0,b1,b2,b3,b4,b5,b6,b7;
    LQ(a0, colc + 0);  LQ(a1, colc + 8);  LQ(a2, colc + 16); LQ(a3, colc + 24);
    LQ(a4, colc + 32); LQ(a5, colc + 40); LQ(a6, colc + 48); LQ(a7, colc + 56);

    // phases 0-3: prologue
    PHASE9(a0,a1,a2,a3,a4,a5,a6,a7, a8, b1,b2,b3,b4,b5,b6,b7, 0,  0);
    PHASE9(a8,b1,b2,b3,b4,b5,b6,b7, b0, a1,a2,a3,a4,a5,a6,a7, 32, 0);
    PHASE9(b0,a1,a2,a3,a4,a5,a6,a7, a8, b1,b2,b3,b4,b5,b6,b7, 64, 0);
    PHASE9(a8,b1,b2,b3,b4,b5,b6,b7, b0, a1,a2,a3,a4,a5,a6,a7, 96, 0);
    // phases 4-29: main (S unused in MODE 1)
#pragma unroll 1
    for (int j = 0; j < 13; ++j) {
      PHASE9(b0,a1,a2,a3,a4,a5,a6,a7, a8, b1,b2,b3,b4,b5,b6,b7, 0, 1);
      PHASE9(a8,b1,b2,b3,b4,b5,b6,b7, b0, a1,a2,a3,a4,a5,a6,a7, 0, 1);
    }
    // phases 30-35: epilogue
    PHASE9(b0,a1,a2,a3,a4,a5,a6,a7, a8, b1,b2,b3,b4,b5,b6,b7, 960,  2);
    PHASE9(a8,b1,b2,b3,b4,b5,b6,b7, b0, a1,a2,a3,a4,a5,a6,a7, 992,  2);
    PHASE9(b0,a1,a2,a3,a4,a5,a6,a7, a8, b1,b2,b3,b4,b5,b6,b7, 1024, 3);
    PHASE9(a8,b1,b2,b3,b4,b5,b6,b7, b0, a1,a2,a3,a4,a5,a6,a7, 1056, 3);
    PHASE9(b0,a1,a2,a3,a4,a5,a6,a7, a8, b1,b2,b3,b4,b5,b6,b7, 1088, 3);
    PHASE9(a8,b1,b2,b3,b4,b5,b6,b7, b0, a1,a2,a3,a4,a5,a6,a7, 1120, 3);
  }
}

extern "C" void kernel_launch(void* const* d_in, const int* in_sizes, int n_in,
                              void* d_out, int out_size, void* d_ws, size_t ws_size,
                              hipStream_t stream) {
  const float* x     = (const float*)d_in[0];
  const float* patts = (const float*)d_in[1];
  float* out         = (float*)d_out;
  const float w = (float)exp(log(0.1) / 64.0);
  dim3 grid(256), block(512);
  hipLaunchKernelGGL(dtw_sg, grid, block, 0, stream, x, patts, out, w);
}

// Round 13
// 45.208 us; speedup vs baseline: 1.1408x; 1.0084x over previous
//
#include <hip/hip_runtime.h>
#include <math.h>

typedef _Float16 half8 __attribute__((ext_vector_type(8)));
typedef _Float16 h2 __attribute__((ext_vector_type(2)));
typedef float    f32x4 __attribute__((ext_vector_type(4)));
typedef unsigned int u32;
typedef unsigned short u16;

#define BIGV 1e30f
#define RQ   57              // uint2 per ring row (456B; 114 words, gcd(114,32)=2)
#define ROWB 456
#define PAIRB (64 * ROWB)

__device__ __forceinline__ u32 dpp_shr1(u32 oldv, u32 src) {
  return (u32)__builtin_amdgcn_update_dpp((int)oldv, (int)src, 0x138, 0xF, 0xF, false);
}
__device__ __forceinline__ float cvtlo(u32 v) {
  union { u16 u; _Float16 h; } c; c.u = (u16)v; return (float)c.h;
}
__device__ __forceinline__ u16 f2h(float f) {
  union { _Float16 h; u16 u; } c; c.h = (_Float16)f; return c.u;
}
__device__ __forceinline__ u32 pkrtz(float a, float b) {
  auto v = __builtin_amdgcn_cvt_pkrtz(a, b);
  union { decltype(v) h; u32 u; } c; c.h = v; return c.u;
}
__device__ __forceinline__ h2 as_h2(u32 u) { union { u32 u; h2 h; } x; x.u = u; return x.h; }

// 12 waves/block (768 thr): per pair pr, SIMD pr hosts {P-even, P-odd, C}.
// Producer split halves per-wave producer issue so the consumer's stalls are
// filled by two independent producer streams. Pipeline/ring = R12 (validated).
__global__ __launch_bounds__(768) void dtw_sg3(
    const float* __restrict__ x,      // (16,16,1024)
    const float* __restrict__ patts,  // (64,16,64)
    float* __restrict__ out,          // (16,64,64,64)
    float wd) {
  __shared__ uint4 xsq[2050];
  __shared__ u16   x2h16[1024];
  __shared__ uint2 ring2[4 * 64 * RQ];   // 116736 B

  const int tid = threadIdx.x, lane = tid & 63, wv = tid >> 6;
  const int b = blockIdx.x >> 4, pg = blockIdx.x & 15;
  const int role = wv >> 2, pr = wv & 3;   // role 0=P-even, 1=P-odd, 2=C
  const int p = pg * 4 + pr;
  const int le = lane & 15, kq = lane >> 4;

  // ---- stage x ----
  {
    const float* xb = x + b * (16 * 1024);
    u16* xh = (u16*)xsq;
    for (int idx = tid; idx < 16384; idx += 768) {
      int d = idx >> 10, t = idx & 1023;
      xh[t * 16 + d] = f2h(xb[idx]);
    }
    if (tid == 0) { xsq[2048] = make_uint4(0,0,0,0); xsq[2049] = make_uint4(0,0,0,0); }
    __syncthreads();
    for (int t = tid; t < 1024; t += 768) {
      uint4 a0 = xsq[2 * t], a1 = xsq[2 * t + 1];
      float s2 = __builtin_amdgcn_fdot2(as_h2(a0.x), as_h2(a0.x), 0.f, false);
      s2 = __builtin_amdgcn_fdot2(as_h2(a0.y), as_h2(a0.y), s2, false);
      s2 = __builtin_amdgcn_fdot2(as_h2(a0.z), as_h2(a0.z), s2, false);
      s2 = __builtin_amdgcn_fdot2(as_h2(a0.w), as_h2(a0.w), s2, false);
      s2 = __builtin_amdgcn_fdot2(as_h2(a1.x), as_h2(a1.x), s2, false);
      s2 = __builtin_amdgcn_fdot2(as_h2(a1.y), as_h2(a1.y), s2, false);
      s2 = __builtin_amdgcn_fdot2(as_h2(a1.z), as_h2(a1.z), s2, false);
      s2 = __builtin_amdgcn_fdot2(as_h2(a1.w), as_h2(a1.w), s2, false);
      x2h16[t] = f2h(s2);
    }
  }
  __syncthreads();   // B0

  if (role < 2) {
    // ================= PRODUCER (even tiles: role 0; odd tiles: role 1) =================
    half8 bf[4];
    {
      const float* pp = patts + p * (16 * 64);
#pragma unroll
      for (int nb = 0; nb < 4; ++nb) {
        float pv[8]; float part = 0.f;
#pragma unroll
        for (int j = 0; j < 8; ++j) {
          float f = (kq < 2) ? pp[(8 * kq + j) * 64 + nb * 16 + le] : 0.f;
          pv[j] = f; part = fmaf(f, f, part);
        }
        part += __shfl_xor(part, 16, 64);
        part += __shfl_xor(part, 32, 64);
        u32 wd0 = pkrtz(-2.f * pv[0], -2.f * pv[1]);
        u32 wd1 = pkrtz(-2.f * pv[2], -2.f * pv[3]);
        u32 wd2 = pkrtz(-2.f * pv[4], -2.f * pv[5]);
        u32 wd3 = pkrtz(-2.f * pv[6], -2.f * pv[7]);
        if (kq == 2) { wd0 = 0x3C00u | ((u32)f2h(part) << 16); wd1 = 0; wd2 = 0; wd3 = 0; }
        union { uint4 q; half8 h; } bu; bu.q = make_uint4(wd0, wd1, wd2, wd3);
        bf[nb] = bu.h;
      }
    }
    // this wave produces every other 16-t tile; byte col advances 64 per PRODUCE
    int colp = 8 * kq + (role == 1 ? 32 : 0);
    const int wpbase = pr * (64 * RQ) + RQ * le;

#define PRODUCE(T0) { \
    int aidx_ = (kq < 2) ? (2 * ((T0) + le) + kq) : 2048; \
    uint4 aq_ = xsq[aidx_]; \
    u32 x2b_ = (u32)x2h16[(T0) + le]; \
    aq_.x = (kq == 2) ? (x2b_ | 0x3C000000u) : aq_.x; \
    union { uint4 q; half8 h; } au_; au_.q = aq_; \
    int wb_ = wpbase + (colp >> 3); \
    _Pragma("unroll") \
    for (int nb_ = 0; nb_ < 4; ++nb_) { \
      f32x4 c_ = {0.f, 0.f, 0.f, 0.f}; \
      c_ = __builtin_amdgcn_mfma_f32_16x16x32_f16(au_.h, bf[nb_], c_, 0, 0, 0); \
      float d0_ = __builtin_amdgcn_sqrtf(fmaxf(c_[0], 1e-12f)); \
      float d1_ = __builtin_amdgcn_sqrtf(fmaxf(c_[1], 1e-12f)); \
      float d2_ = __builtin_amdgcn_sqrtf(fmaxf(c_[2], 1e-12f)); \
      float d3_ = __builtin_amdgcn_sqrtf(fmaxf(c_[3], 1e-12f)); \
      uint2 st_; st_.x = pkrtz(d0_, d1_); st_.y = pkrtz(d2_, d3_); \
      ring2[wb_ + 16 * RQ * nb_] = st_; \
    } \
    colp += 64; if (colp >= 448) colp -= 448; }

    if (role == 0) { PRODUCE(0);  PRODUCE(32); }   // tiles 0,2
    else           { PRODUCE(16); PRODUCE(48); }   // tiles 1,3
    __syncthreads();   // B1
#pragma unroll 1
    for (int k = 0; k < 30; ++k) {       // phase k: tile 2k+4 (even wave) / 2k+5 (odd wave)
      if (role == 0) { PRODUCE(32 * k + 64); }
      else           { PRODUCE(32 * k + 80); }
      __syncthreads();
    }
    for (int k = 0; k < 6; ++k) __syncthreads();   // idle phases 30-35

  } else {
    // ================= CONSUMER (stagger-2, identical to R12) =================
    const char* crow = (const char*)ring2 + pr * PAIRB + lane * ROWB;
    const int  l2 = 2 * lane;
    u32 byte0 = (u32)((448 - 4 * lane) % 448);
    u32 colc  = byte0 & ~7u;
    const bool sel2 = (lane & 1) != 0;
    const int bigbits = __float_as_int(BIGV);
    float prev = BIGV, q1 = BIGV, q2 = BIGV, q3 = BIGV, pend = 0.f;
    float* oprow = out + ((b * 64 + p) * 64 + lane) * 64;

#define WRAP448(X) ((X) >= 448u ? (X) - 448u : (X))
#define LQ(DST, OFF) { u32 o_ = WRAP448((u32)(OFF)); DST = *(const uint2*)(crow + o_); }

#define DPS(S, D, MODE) { \
    float dist_ = (D); \
    float m_ = fminf(fminf(prev, q2), q3); \
    if ((MODE) == 0) m_ = (m_ >= 0.5e30f) ? 0.f : m_; \
    float val_ = fmaf(wd, m_, dist_); \
    float cur_ = val_; \
    if ((MODE) == 0) cur_ = ((S) >= l2) ? val_ : BIGV; \
    if ((MODE) == 3) cur_ = (l2 >= (S) - 1023) ? val_ : BIGV; \
    if ((MODE) >= 2) { \
      if (((S) & 1) == 0) { pend = val_; } \
      else { int t_ = (S) - l2; if ((u32)(t_ - 961) < 63u) \
        *(float2*)(oprow + (t_ - 961)) = make_float2(pend, val_); } \
    } \
    q3 = q2; q2 = q1; \
    q1 = __int_as_float((int)dpp_shr1((u32)bigbits, (u32)__float_as_int(cur_))); \
    prev = cur_; }

#define G16(G0, G1, G2, G3, G4, S0, MODE) { \
    u32 w0 = sel2 ? G0.y : G0.x, w1 = sel2 ? G1.x : G0.y; \
    u32 w2 = sel2 ? G1.y : G1.x, w3 = sel2 ? G2.x : G1.y; \
    u32 w4 = sel2 ? G2.y : G2.x, w5 = sel2 ? G3.x : G2.y; \
    u32 w6 = sel2 ? G3.y : G3.x, w7 = sel2 ? G4.x : G3.y; \
    DPS((S0)+0,  cvtlo(w0), MODE); DPS((S0)+1,  cvtlo(w0 >> 16), MODE); \
    DPS((S0)+2,  cvtlo(w1), MODE); DPS((S0)+3,  cvtlo(w1 >> 16), MODE); \
    DPS((S0)+4,  cvtlo(w2), MODE); DPS((S0)+5,  cvtlo(w2 >> 16), MODE); \
    DPS((S0)+6,  cvtlo(w3), MODE); DPS((S0)+7,  cvtlo(w3 >> 16), MODE); \
    DPS((S0)+8,  cvtlo(w4), MODE); DPS((S0)+9,  cvtlo(w4 >> 16), MODE); \
    DPS((S0)+10, cvtlo(w5), MODE); DPS((S0)+11, cvtlo(w5 >> 16), MODE); \
    DPS((S0)+12, cvtlo(w6), MODE); DPS((S0)+13, cvtlo(w6 >> 16), MODE); \
    DPS((S0)+14, cvtlo(w7), MODE); DPS((S0)+15, cvtlo(w7 >> 16), MODE); }

#define PHASE9(C0,C1,C2,C3,C4,C5,C6,C7, D8, N1,N2,N3,N4,N5,N6,N7, S0, MODE) { \
    LQ(D8, colc + 64); \
    G16(C0, C1, C2, C3, C4, S0, MODE); \
    LQ(N1, colc + 72);  LQ(N2, colc + 80);  LQ(N3, colc + 88); \
    LQ(N4, colc + 96);  LQ(N5, colc + 104); LQ(N6, colc + 112); LQ(N7, colc + 120); \
    G16(C4, C5, C6, C7, D8, (S0) + 16, MODE); \
    colc = WRAP448(colc + 64); \
    __builtin_amdgcn_s_barrier(); }

    __builtin_amdgcn_s_barrier();   // B1: tiles 0-3 ready
    uint2 a0,a1,a2,a3,a4,a5,a6,a7,a8, b0,b1,b2,b3,b4,b5,b6,b7;
    LQ(a0, colc + 0);  LQ(a1, colc + 8);  LQ(a2, colc + 16); LQ(a3, colc + 24);
    LQ(a4, colc + 32); LQ(a5, colc + 40); LQ(a6, colc + 48); LQ(a7, colc + 56);

    PHASE9(a0,a1,a2,a3,a4,a5,a6,a7, a8, b1,b2,b3,b4,b5,b6,b7, 0,  0);
    PHASE9(a8,b1,b2,b3,b4,b5,b6,b7, b0, a1,a2,a3,a4,a5,a6,a7, 32, 0);
    PHASE9(b0,a1,a2,a3,a4,a5,a6,a7, a8, b1,b2,b3,b4,b5,b6,b7, 64, 0);
    PHASE9(a8,b1,b2,b3,b4,b5,b6,b7, b0, a1,a2,a3,a4,a5,a6,a7, 96, 0);
#pragma unroll 1
    for (int j = 0; j < 13; ++j) {
      PHASE9(b0,a1,a2,a3,a4,a5,a6,a7, a8, b1,b2,b3,b4,b5,b6,b7, 0, 1);
      PHASE9(a8,b1,b2,b3,b4,b5,b6,b7, b0, a1,a2,a3,a4,a5,a6,a7, 0, 1);
    }
    PHASE9(b0,a1,a2,a3,a4,a5,a6,a7, a8, b1,b2,b3,b4,b5,b6,b7, 960,  2);
    PHASE9(a8,b1,b2,b3,b4,b5,b6,b7, b0, a1,a2,a3,a4,a5,a6,a7, 992,  2);
    PHASE9(b0,a1,a2,a3,a4,a5,a6,a7, a8, b1,b2,b3,b4,b5,b6,b7, 1024, 3);
    PHASE9(a8,b1,b2,b3,b4,b5,b6,b7, b0, a1,a2,a3,a4,a5,a6,a7, 1056, 3);
    PHASE9(b0,a1,a2,a3,a4,a5,a6,a7, a8, b1,b2,b3,b4,b5,b6,b7, 1088, 3);
    PHASE9(a8,b1,b2,b3,b4,b5,b6,b7, b0, a1,a2,a3,a4,a5,a6,a7, 1120, 3);
  }
}

extern "C" void kernel_launch(void* const* d_in, const int* in_sizes, int n_in,
                              void* d_out, int out_size, void* d_ws, size_t ws_size,
                              hipStream_t stream) {
  const float* x     = (const float*)d_in[0];
  const float* patts = (const float*)d_in[1];
  float* out         = (float*)d_out;
  const float w = (float)exp(log(0.1) / 64.0);
  dim3 grid(256), block(768);
  hipLaunchKernelGGL(dtw_sg3, grid, block, 0, stream, x, patts, out, w);
}

// Round 14
// 44.410 us; speedup vs baseline: 1.1613x; 1.0180x over previous
//
#include <hip/hip_runtime.h>
#include <math.h>

typedef _Float16 half8 __attribute__((ext_vector_type(8)));
typedef _Float16 h2 __attribute__((ext_vector_type(2)));
typedef float    f32x4 __attribute__((ext_vector_type(4)));
typedef unsigned int u32;
typedef unsigned short u16;

#define BIGV 1e30f
#define RQ   57              // uint2 per ring row (456B; 114 words)
#define ROWB 456
#define PAIRB (64 * ROWB)

__device__ __forceinline__ u32 dpp_shr1(u32 oldv, u32 src) {
  return (u32)__builtin_amdgcn_update_dpp((int)oldv, (int)src, 0x138, 0xF, 0xF, false);
}
__device__ __forceinline__ float cvtlo(u32 v) {
  union { u16 u; _Float16 h; } c; c.u = (u16)v; return (float)c.h;
}
__device__ __forceinline__ u16 f2h(float f) {
  union { _Float16 h; u16 u; } c; c.h = (_Float16)f; return c.u;
}
__device__ __forceinline__ u32 pkrtz(float a, float b) {
  auto v = __builtin_amdgcn_cvt_pkrtz(a, b);
  union { decltype(v) h; u32 u; } c; c.h = v; return c.u;
}
__device__ __forceinline__ h2 as_h2(u32 u) { union { u32 u; h2 h; } x; x.u = u; return x.h; }

// R13 structure (12 waves: {P-even,P-odd,C} per pair per SIMD) with 64-step
// phases: barrier every 64 DP steps (19 barriers vs 37). Producer lead = 8
// tiles; phase k writes tiles 4k+8..4k+11, consumer reads <= 4k+7 (race-free,
// 12 live tiles < 14-tile window).
__global__ __launch_bounds__(768) void dtw_sg4(
    const float* __restrict__ x,      // (16,16,1024)
    const float* __restrict__ patts,  // (64,16,64)
    float* __restrict__ out,          // (16,64,64,64)
    float wd) {
  __shared__ uint4 xsq[2050];
  __shared__ u16   x2h16[1024];
  __shared__ uint2 ring2[4 * 64 * RQ];   // 116736 B

  const int tid = threadIdx.x, lane = tid & 63, wv = tid >> 6;
  const int b = blockIdx.x >> 4, pg = blockIdx.x & 15;
  const int role = wv >> 2, pr = wv & 3;   // 0=P-even, 1=P-odd, 2=C
  const int p = pg * 4 + pr;
  const int le = lane & 15, kq = lane >> 4;

  // ---- stage x ----
  {
    const float* xb = x + b * (16 * 1024);
    u16* xh = (u16*)xsq;
    for (int idx = tid; idx < 16384; idx += 768) {
      int d = idx >> 10, t = idx & 1023;
      xh[t * 16 + d] = f2h(xb[idx]);
    }
    if (tid == 0) { xsq[2048] = make_uint4(0,0,0,0); xsq[2049] = make_uint4(0,0,0,0); }
    __syncthreads();
    for (int t = tid; t < 1024; t += 768) {
      uint4 a0 = xsq[2 * t], a1 = xsq[2 * t + 1];
      float s2 = __builtin_amdgcn_fdot2(as_h2(a0.x), as_h2(a0.x), 0.f, false);
      s2 = __builtin_amdgcn_fdot2(as_h2(a0.y), as_h2(a0.y), s2, false);
      s2 = __builtin_amdgcn_fdot2(as_h2(a0.z), as_h2(a0.z), s2, false);
      s2 = __builtin_amdgcn_fdot2(as_h2(a0.w), as_h2(a0.w), s2, false);
      s2 = __builtin_amdgcn_fdot2(as_h2(a1.x), as_h2(a1.x), s2, false);
      s2 = __builtin_amdgcn_fdot2(as_h2(a1.y), as_h2(a1.y), s2, false);
      s2 = __builtin_amdgcn_fdot2(as_h2(a1.z), as_h2(a1.z), s2, false);
      s2 = __builtin_amdgcn_fdot2(as_h2(a1.w), as_h2(a1.w), s2, false);
      x2h16[t] = f2h(s2);
    }
  }
  __syncthreads();   // B0

  if (role < 2) {
    // ================= PRODUCER =================
    half8 bf[4];
    {
      const float* pp = patts + p * (16 * 64);
#pragma unroll
      for (int nb = 0; nb < 4; ++nb) {
        float pv[8]; float part = 0.f;
#pragma unroll
        for (int j = 0; j < 8; ++j) {
          float f = (kq < 2) ? pp[(8 * kq + j) * 64 + nb * 16 + le] : 0.f;
          pv[j] = f; part = fmaf(f, f, part);
        }
        part += __shfl_xor(part, 16, 64);
        part += __shfl_xor(part, 32, 64);
        u32 wd0 = pkrtz(-2.f * pv[0], -2.f * pv[1]);
        u32 wd1 = pkrtz(-2.f * pv[2], -2.f * pv[3]);
        u32 wd2 = pkrtz(-2.f * pv[4], -2.f * pv[5]);
        u32 wd3 = pkrtz(-2.f * pv[6], -2.f * pv[7]);
        if (kq == 2) { wd0 = 0x3C00u | ((u32)f2h(part) << 16); wd1 = 0; wd2 = 0; wd3 = 0; }
        union { uint4 q; half8 h; } bu; bu.q = make_uint4(wd0, wd1, wd2, wd3);
        bf[nb] = bu.h;
      }
    }
    int colp = 8 * kq + (role == 1 ? 32 : 0);
    const int wpbase = pr * (64 * RQ) + RQ * le;

#define PRODUCE(T0) { \
    int aidx_ = (kq < 2) ? (2 * ((T0) + le) + kq) : 2048; \
    uint4 aq_ = xsq[aidx_]; \
    u32 x2b_ = (u32)x2h16[(T0) + le]; \
    aq_.x = (kq == 2) ? (x2b_ | 0x3C000000u) : aq_.x; \
    union { uint4 q; half8 h; } au_; au_.q = aq_; \
    int wb_ = wpbase + (colp >> 3); \
    _Pragma("unroll") \
    for (int nb_ = 0; nb_ < 4; ++nb_) { \
      f32x4 c_ = {0.f, 0.f, 0.f, 0.f}; \
      c_ = __builtin_amdgcn_mfma_f32_16x16x32_f16(au_.h, bf[nb_], c_, 0, 0, 0); \
      float d0_ = __builtin_amdgcn_sqrtf(fmaxf(c_[0], 1e-12f)); \
      float d1_ = __builtin_amdgcn_sqrtf(fmaxf(c_[1], 1e-12f)); \
      float d2_ = __builtin_amdgcn_sqrtf(fmaxf(c_[2], 1e-12f)); \
      float d3_ = __builtin_amdgcn_sqrtf(fmaxf(c_[3], 1e-12f)); \
      uint2 st_; st_.x = pkrtz(d0_, d1_); st_.y = pkrtz(d2_, d3_); \
      ring2[wb_ + 16 * RQ * nb_] = st_; \
    } \
    colp += 64; if (colp >= 448) colp -= 448; }

    // lead = 8 tiles: even wave 0,2,4,6; odd wave 1,3,5,7
    if (role == 0) { PRODUCE(0);  PRODUCE(32); PRODUCE(64);  PRODUCE(96); }
    else           { PRODUCE(16); PRODUCE(48); PRODUCE(80);  PRODUCE(112); }
    __syncthreads();   // B1
#pragma unroll 1
    for (int k = 0; k < 14; ++k) {   // phase k: tiles 4k+8..4k+11
      if (role == 0) { PRODUCE(64 * k + 128); PRODUCE(64 * k + 160); }
      else           { PRODUCE(64 * k + 144); PRODUCE(64 * k + 176); }
      __syncthreads();
    }
    __syncthreads(); __syncthreads(); __syncthreads(); __syncthreads();  // idle 14-17

  } else {
    // ================= CONSUMER (stagger-2, 64-step phases) =================
    const char* crow = (const char*)ring2 + pr * PAIRB + lane * ROWB;
    const int  l2 = 2 * lane;
    u32 byte0 = (u32)((448 - 4 * lane) % 448);
    u32 colc  = byte0 & ~7u;
    const bool sel2 = (lane & 1) != 0;
    const int bigbits = __float_as_int(BIGV);
    float prev = BIGV, q1 = BIGV, q2 = BIGV, q3 = BIGV, pend = 0.f;
    float* oprow = out + ((b * 64 + p) * 64 + lane) * 64;

#define WRAP448(X) ((X) >= 448u ? (X) - 448u : (X))
#define LQ(DST, OFF) { u32 o_ = WRAP448((u32)(OFF)); DST = *(const uint2*)(crow + o_); }

#define DPS(S, D, MODE) { \
    float dist_ = (D); \
    float m_ = fminf(fminf(prev, q2), q3); \
    if ((MODE) == 0) m_ = (m_ >= 0.5e30f) ? 0.f : m_; \
    float val_ = fmaf(wd, m_, dist_); \
    float cur_ = val_; \
    if ((MODE) == 0) cur_ = ((S) >= l2) ? val_ : BIGV; \
    if ((MODE) == 3) cur_ = (l2 >= (S) - 1023) ? val_ : BIGV; \
    if ((MODE) >= 2) { \
      if (((S) & 1) == 0) { pend = val_; } \
      else { int t_ = (S) - l2; if ((u32)(t_ - 961) < 63u) \
        *(float2*)(oprow + (t_ - 961)) = make_float2(pend, val_); } \
    } \
    q3 = q2; q2 = q1; \
    q1 = __int_as_float((int)dpp_shr1((u32)bigbits, (u32)__float_as_int(cur_))); \
    prev = cur_; }

#define G16(G0, G1, G2, G3, G4, S0, MODE) { \
    u32 w0 = sel2 ? G0.y : G0.x, w1 = sel2 ? G1.x : G0.y; \
    u32 w2 = sel2 ? G1.y : G1.x, w3 = sel2 ? G2.x : G1.y; \
    u32 w4 = sel2 ? G2.y : G2.x, w5 = sel2 ? G3.x : G2.y; \
    u32 w6 = sel2 ? G3.y : G3.x, w7 = sel2 ? G4.x : G3.y; \
    DPS((S0)+0,  cvtlo(w0), MODE); DPS((S0)+1,  cvtlo(w0 >> 16), MODE); \
    DPS((S0)+2,  cvtlo(w1), MODE); DPS((S0)+3,  cvtlo(w1 >> 16), MODE); \
    DPS((S0)+4,  cvtlo(w2), MODE); DPS((S0)+5,  cvtlo(w2 >> 16), MODE); \
    DPS((S0)+6,  cvtlo(w3), MODE); DPS((S0)+7,  cvtlo(w3 >> 16), MODE); \
    DPS((S0)+8,  cvtlo(w4), MODE); DPS((S0)+9,  cvtlo(w4 >> 16), MODE); \
    DPS((S0)+10, cvtlo(w5), MODE); DPS((S0)+11, cvtlo(w5 >> 16), MODE); \
    DPS((S0)+12, cvtlo(w6), MODE); DPS((S0)+13, cvtlo(w6 >> 16), MODE); \
    DPS((S0)+14, cvtlo(w7), MODE); DPS((S0)+15, cvtlo(w7 >> 16), MODE); }

    // 32-step sub-phase; BAR=1 adds the s_barrier (once per 64 steps)
#define SUBPH(C0,C1,C2,C3,C4,C5,C6,C7, D8, N1,N2,N3,N4,N5,N6,N7, S0, MODE, BAR) { \
    LQ(D8, colc + 64); \
    G16(C0, C1, C2, C3, C4, S0, MODE); \
    LQ(N1, colc + 72);  LQ(N2, colc + 80);  LQ(N3, colc + 88); \
    LQ(N4, colc + 96);  LQ(N5, colc + 104); LQ(N6, colc + 112); LQ(N7, colc + 120); \
    G16(C4, C5, C6, C7, D8, (S0) + 16, MODE); \
    colc = WRAP448(colc + 64); \
    if (BAR) __builtin_amdgcn_s_barrier(); }

    __builtin_amdgcn_s_barrier();   // B1: tiles 0-7 ready
    uint2 a0,a1,a2,a3,a4,a5,a6,a7,a8, b0,b1,b2,b3,b4,b5,b6,b7;
    LQ(a0, colc + 0);  LQ(a1, colc + 8);  LQ(a2, colc + 16); LQ(a3, colc + 24);
    LQ(a4, colc + 32); LQ(a5, colc + 40); LQ(a6, colc + 48); LQ(a7, colc + 56);

    // sub-phases 0-3: prologue (s<128)
    SUBPH(a0,a1,a2,a3,a4,a5,a6,a7, a8, b1,b2,b3,b4,b5,b6,b7, 0,  0, 0);
    SUBPH(a8,b1,b2,b3,b4,b5,b6,b7, b0, a1,a2,a3,a4,a5,a6,a7, 32, 0, 1);
    SUBPH(b0,a1,a2,a3,a4,a5,a6,a7, a8, b1,b2,b3,b4,b5,b6,b7, 64, 0, 0);
    SUBPH(a8,b1,b2,b3,b4,b5,b6,b7, b0, a1,a2,a3,a4,a5,a6,a7, 96, 0, 1);
    // sub-phases 4-29: main
#pragma unroll 1
    for (int j = 0; j < 13; ++j) {
      SUBPH(b0,a1,a2,a3,a4,a5,a6,a7, a8, b1,b2,b3,b4,b5,b6,b7, 0, 1, 0);
      SUBPH(a8,b1,b2,b3,b4,b5,b6,b7, b0, a1,a2,a3,a4,a5,a6,a7, 0, 1, 1);
    }
    // sub-phases 30-35: epilogue
    SUBPH(b0,a1,a2,a3,a4,a5,a6,a7, a8, b1,b2,b3,b4,b5,b6,b7, 960,  2, 0);
    SUBPH(a8,b1,b2,b3,b4,b5,b6,b7, b0, a1,a2,a3,a4,a5,a6,a7, 992,  2, 1);
    SUBPH(b0,a1,a2,a3,a4,a5,a6,a7, a8, b1,b2,b3,b4,b5,b6,b7, 1024, 3, 0);
    SUBPH(a8,b1,b2,b3,b4,b5,b6,b7, b0, a1,a2,a3,a4,a5,a6,a7, 1056, 3, 1);
    SUBPH(b0,a1,a2,a3,a4,a5,a6,a7, a8, b1,b2,b3,b4,b5,b6,b7, 1088, 3, 0);
    SUBPH(a8,b1,b2,b3,b4,b5,b6,b7, b0, a1,a2,a3,a4,a5,a6,a7, 1120, 3, 1);
  }
}

extern "C" void kernel_launch(void* const* d_in, const int* in_sizes, int n_in,
                              void* d_out, int out_size, void* d_ws, size_t ws_size,
                              hipStream_t stream) {
  const float* x     = (const float*)d_in[0];
  const float* patts = (const float*)d_in[1];
  float* out         = (float*)d_out;
  const float w = (float)exp(log(0.1) / 64.0);
  dim3 grid(256), block(768);
  hipLaunchKernelGGL(dtw_sg4, grid, block, 0, stream, x, patts, out, w);
}